// Round 1
// 3192.156 us; speedup vs baseline: 1.3171x; 1.3171x over previous
//
#include <hip/hip_runtime.h>

#define BB 256
#define TT 256
#define II 512
#define HH 1024

typedef _Float16 h16;
typedef __attribute__((ext_vector_type(4))) _Float16 h16x4;
typedef __attribute__((ext_vector_type(8))) _Float16 h16x8;
typedef __attribute__((ext_vector_type(4))) float f32x4;
typedef __attribute__((ext_vector_type(4))) unsigned int u32x4;

#define KPADH 1032                 // h16 elems per Abuf row (1024 + 8 pad) = 2064 B
#define ABUF_BYTES 66048           // 32 * 1032 * 2
#define PRE_OFF 66048
#define SMEM_BYTES 99840           // 66048 + 8*32*33*4

// workspace layout (bytes) — unchanged
#define WX_OFF   0UL
#define WH_OFF   4194304UL
#define BIAS_OFF 12582912UL
#define W1T_OFF  12599296UL
#define HBUF_OFF 12861440UL
#define ARR_OFF  13910016UL
#define XH_OFF   13914112UL
#define XH_END   81022976UL

#define HSTRIDE (BB * HH)

__device__ __forceinline__ float sigm(float x) { return 1.0f / (1.0f + __expf(-x)); }
__device__ __forceinline__ float tanh_(float x) { float e = __expf(2.0f * x); return 1.0f - 2.0f / (e + 1.0f); }

// ---------------- prep: cast/pack weights ----------------
__global__ void k_prep(const float* __restrict__ Wfx, const float* __restrict__ Wfh, const float* __restrict__ bf,
                       const float* __restrict__ Wix, const float* __restrict__ Wih, const float* __restrict__ bi,
                       const float* __restrict__ Wox, const float* __restrict__ Woh, const float* __restrict__ bo,
                       const float* __restrict__ Wcx, const float* __restrict__ Wch, const float* __restrict__ bc,
                       const float* __restrict__ W1,
                       h16* __restrict__ Wx, h16* __restrict__ Wh, float* __restrict__ bias, float* __restrict__ W1T)
{
  const long NWX = 4096L * 512, NWH = 4096L * 1024, NB = 4096, NW1 = 1024L * 64;
  const long total = NWX + NWH + NB + NW1;
  for (long id = blockIdx.x * 256L + threadIdx.x; id < total; id += gridDim.x * 256L) {
    if (id < NWX) {
      long n = id >> 9, k = id & 511;
      long g = n >> 10, j = n & 1023;
      const float* s = (g == 0) ? Wfx : (g == 1) ? Wix : (g == 2) ? Wox : Wcx;
      Wx[id] = (h16)s[j * II + k];
    } else if (id < NWX + NWH) {
      long i2 = id - NWX;
      long n = i2 >> 10, k = i2 & 1023;
      long g = n >> 10, j = n & 1023;
      const float* s = (g == 0) ? Wfh : (g == 1) ? Wih : (g == 2) ? Woh : Wch;
      Wh[i2] = (h16)s[j * HH + k];
    } else if (id < NWX + NWH + NB) {
      long n = id - NWX - NWH;
      long g = n >> 10, j = n & 1023;
      const float* s = (g == 0) ? bf : (g == 1) ? bi : (g == 2) ? bo : bc;
      bias[n] = s[j];
    } else {
      long i2 = id - NWX - NWH - NB;
      long k = i2 >> 6, n = i2 & 63;
      W1T[i2] = W1[n * HH + k];
    }
  }
}

// ---------------- prep: cast x to fp16 ----------------
__global__ void k_castx(const float* __restrict__ x, h16* __restrict__ xh) {
  const long n = (long)BB * TT * II;
  for (long i = (blockIdx.x * 256L + threadIdx.x) * 4; i < n; i += gridDim.x * 1024L) {
    float4 v = *(const float4*)(x + i);
    h16x4 o = {(h16)v.x, (h16)v.y, (h16)v.z, (h16)v.w};
    *(h16x4*)(xh + i) = o;
  }
}

// ---------------- persistent LSTM kernel ----------------
// 8 groups x 32 batch rows; 32 WGs per group; WG = 32 rows x 32 cols x 4 gates.
// group = bx>>5, nslice = bx&31 so nslice&7 == XCD: the 4 WGs per XCD that share
// a col-slice keep their 512 KB Wx slice L2-resident.
// 8 waves = 4 gates x 2 K-halves (split-K): each wave streams only K/2 of the
// A-slab from LDS (halves the LDS read stream); partial sums meet in Pre.
// Wh fragments register-resident (128 VGPRs/wave) for the whole t-loop.
// Per step: poll -> issue 8 coherent staging loads -> x-GEMM (staging flies
// underneath) -> single vmcnt(0) -> LDS write -> h-GEMM -> Pre exchange ->
// elementwise -> coherent h store -> publish. Parity double-buffered hbuf:
// WAR closed by the slot-poll induction (identical to prior proven scheme).
template <int USE_XH>
__global__ __launch_bounds__(512, 1) void k_lstm(
    const float* __restrict__ x32, const h16* __restrict__ x16,
    const h16* __restrict__ Wx, const h16* __restrict__ Wh,
    const float* __restrict__ bias,
    h16* __restrict__ hbuf, unsigned int* __restrict__ arr)
{
  extern __shared__ char smem[];
  h16* Abuf = (h16*)smem;                 // [32][KPADH] fp16
  float* Pre = (float*)(smem + PRE_OFF);  // [8][32][33] f32, slab = g*2+kh

  const int tid = threadIdx.x;
  const int wid = tid >> 6;   // 0..7
  const int lane = tid & 63;
  const int lm = lane & 15;   // MFMA row/col within 16
  const int lq = lane >> 4;   // k-quad

  const int bx = blockIdx.x;
  const int group = bx >> 5;      // 0..7 (32 batch rows each)
  const int nslice = bx & 31;     // col slice 0..31 (nslice&7 == XCD)
  const int r0 = group * 32;
  const int hc0 = nslice * 32;

  const int g = wid >> 1;          // gate 0..3
  const int kh = wid & 1;          // K-half 0..1

  const int ng0 = g * HH + hc0 + lm;        // packed-weight row, col-tile 0
  const int ng1 = ng0 + 16;                 // col-tile 1
  const float bs0 = (kh == 0) ? bias[ng0] : 0.f;
  const float bs1 = (kh == 0) ? bias[ng1] : 0.f;

  const h16* WxB0 = Wx + (size_t)ng0 * II + kh * 256 + lq * 8;
  const h16* WxB1 = Wx + (size_t)ng1 * II + kh * 256 + lq * 8;

  // ---- Wh fragments into registers ONCE (2 col-tiles x 16 kk = 128 VGPRs) ----
  h16x8 wh0[16], wh1[16];
  {
    const h16* p0 = Wh + (size_t)ng0 * HH + kh * 512 + lq * 8;
    const h16* p1 = Wh + (size_t)ng1 * HH + kh * 512 + lq * 8;
#pragma unroll
    for (int kk = 0; kk < 16; ++kk) {
      wh0[kk] = *(const h16x8*)(p0 + kk * 32);
      wh1[kk] = *(const h16x8*)(p1 + kk * 32);
    }
  }

  const size_t TI = (size_t)TT * II;
  const float* xr32_0 = x32 + (size_t)(r0 + lm) * TI + kh * 256 + lq * 8;
  const float* xr32_1 = xr32_0 + 16 * TI;
  const h16* xr16_0 = x16 + (size_t)(r0 + lm) * TI + kh * 256 + lq * 8;
  const h16* xr16_1 = xr16_0 + 16 * TI;

  const int aB0 = lm * KPADH + kh * 512 + lq * 8;          // rt=0 rows
  const int aB1 = (16 + lm) * KPADH + kh * 512 + lq * 8;   // rt=1 rows

  const int urow = tid >> 4;        // 0..31
  const int ucolp = (tid & 15) * 2; // 0,2,..,30
  float cst[2] = {0.f, 0.f};

  unsigned int* slots = arr + group * 32;   // 32 producer slots per group
  unsigned int* myslot = slots + nslice;

  for (int t = 0; t < TT; ++t) {
    f32x4 a00 = {bs0, bs0, bs0, bs0};
    f32x4 a01 = {bs1, bs1, bs1, bs1};
    f32x4 a10 = a00;
    f32x4 a11 = a01;

    u32x4 stg[8];
    if (t > 0) {
      // ---- group barrier: lanes 0..31 of wave0 poll producer slots ----
      if (tid < 32) {
        const unsigned int* sp = slots + tid;
        unsigned int v;
        do {
          asm volatile("global_load_dword %0, %1, off sc0 sc1\n\t"
                       "s_waitcnt vmcnt(0)"
                       : "=v"(v) : "v"(sp) : "memory");
        } while (__any(v < (unsigned int)t));
      }
      __syncthreads();
      // ---- issue staging of h(t-1) (IC-coherent); completes under x-GEMM ----
      {
        const h16* hs = hbuf + (size_t)((t - 1) & 1) * HSTRIDE + (size_t)r0 * HH;
#pragma unroll
        for (int j = 0; j < 8; ++j) {
          int c = tid + j * 512;            // 0..4095 granules of 16B
          const h16* p = hs + (size_t)(c >> 7) * HH + (c & 127) * 8;
          asm volatile("global_load_dwordx4 %0, %1, off sc0 sc1"
                       : "=v"(stg[j]) : "v"(p) : "memory");
        }
      }
    }

    // ---- x-part (independent of h; staging loads fly underneath) ----
#pragma unroll 2
    for (int kk = 0; kk < 8; ++kk) {
      h16x8 xa0, xa1;
      if (USE_XH) {
        xa0 = *(const h16x8*)(xr16_0 + (size_t)t * II + kk * 32);
        xa1 = *(const h16x8*)(xr16_1 + (size_t)t * II + kk * 32);
      } else {
        const float* p0 = xr32_0 + (size_t)t * II + kk * 32;
        const float* p1 = xr32_1 + (size_t)t * II + kk * 32;
        float4 u0 = *(const float4*)(p0), v0 = *(const float4*)(p0 + 4);
        float4 u1 = *(const float4*)(p1), v1 = *(const float4*)(p1 + 4);
        xa0 = (h16x8){(h16)u0.x, (h16)u0.y, (h16)u0.z, (h16)u0.w, (h16)v0.x, (h16)v0.y, (h16)v0.z, (h16)v0.w};
        xa1 = (h16x8){(h16)u1.x, (h16)u1.y, (h16)u1.z, (h16)u1.w, (h16)v1.x, (h16)v1.y, (h16)v1.z, (h16)v1.w};
      }
      h16x8 xb0 = *(const h16x8*)(WxB0 + kk * 32);
      h16x8 xb1 = *(const h16x8*)(WxB1 + kk * 32);
      a00 = __builtin_amdgcn_mfma_f32_16x16x32_f16(xa0, xb0, a00, 0, 0, 0);
      a01 = __builtin_amdgcn_mfma_f32_16x16x32_f16(xa0, xb1, a01, 0, 0, 0);
      a10 = __builtin_amdgcn_mfma_f32_16x16x32_f16(xa1, xb0, a10, 0, 0, 0);
      a11 = __builtin_amdgcn_mfma_f32_16x16x32_f16(xa1, xb1, a11, 0, 0, 0);
    }

    if (t > 0) {
      // ---- drain staging, unload to LDS (single wait wall) ----
      asm volatile("s_waitcnt vmcnt(0)" ::: "memory");
#pragma unroll
      for (int j = 0; j < 8; ++j) {
        int c = tid + j * 512;
        *(u32x4*)(Abuf + (c >> 7) * KPADH + (c & 127) * 8) = stg[j];
      }
      __syncthreads();
      // ---- h-part GEMM, this wave's K-half only (B in registers) ----
#pragma unroll
      for (int kk = 0; kk < 16; ++kk) {
        h16x8 ha0 = *(const h16x8*)(Abuf + aB0 + kk * 32);
        h16x8 ha1 = *(const h16x8*)(Abuf + aB1 + kk * 32);
        a00 = __builtin_amdgcn_mfma_f32_16x16x32_f16(ha0, wh0[kk], a00, 0, 0, 0);
        a01 = __builtin_amdgcn_mfma_f32_16x16x32_f16(ha0, wh1[kk], a01, 0, 0, 0);
        a10 = __builtin_amdgcn_mfma_f32_16x16x32_f16(ha1, wh0[kk], a10, 0, 0, 0);
        a11 = __builtin_amdgcn_mfma_f32_16x16x32_f16(ha1, wh1[kk], a11, 0, 0, 0);
      }
    }

    // ---- partial preacts -> LDS (cross-wave gate + split-K exchange) ----
    {
      float* Pg = Pre + (size_t)(g * 2 + kh) * 32 * 33;
#pragma unroll
      for (int i = 0; i < 4; ++i) {
        int rA = lq * 4 + i;
        Pg[rA * 33 + lm]              = a00[i];
        Pg[rA * 33 + 16 + lm]         = a01[i];
        Pg[(16 + rA) * 33 + lm]       = a10[i];
        Pg[(16 + rA) * 33 + 16 + lm]  = a11[i];
      }
    }
    __syncthreads();
    // ---- elementwise c/h update (c persistent in regs), write h to buf[t&1] ----
    {
      float hv[2];
#pragma unroll
      for (int cc = 0; cc < 2; ++cc) {
        int col = ucolp + cc;
        float fp = Pre[(0 * 32 + urow) * 33 + col] + Pre[(1 * 32 + urow) * 33 + col];
        float ip = Pre[(2 * 32 + urow) * 33 + col] + Pre[(3 * 32 + urow) * 33 + col];
        float op = Pre[(4 * 32 + urow) * 33 + col] + Pre[(5 * 32 + urow) * 33 + col];
        float cp = Pre[(6 * 32 + urow) * 33 + col] + Pre[(7 * 32 + urow) * 33 + col];
        float c2 = sigm(fp) * cst[cc] + sigm(ip) * tanh_(cp);
        cst[cc] = c2;
        hv[cc] = sigm(op) * tanh_(c2);
      }
      union { h16 h[2]; unsigned int u; } pk;
      pk.h[0] = (h16)hv[0]; pk.h[1] = (h16)hv[1];
      const h16* hp = hbuf + (size_t)(t & 1) * HSTRIDE + (size_t)(r0 + urow) * HH + hc0 + ucolp;
      asm volatile("global_store_dword %0, %1, off sc0 sc1"
                   :: "v"(hp), "v"(pk.u) : "memory");
    }
    __builtin_amdgcn_s_waitcnt(0);   // h stores complete at IC
    __syncthreads();                 // ...for ALL waves of this WG
    if (tid == 0) {                  // publish: plain store, no RMW
      unsigned int val = (unsigned int)(t + 1);
      asm volatile("global_store_dword %0, %1, off sc0 sc1"
                   :: "v"(myslot), "v"(val) : "memory");
    }
  }
}

// ---------------- head: relu -> [64] relu -> [10] softmax ----------------
__global__ void k_head(const h16* __restrict__ hbuf, const float* __restrict__ W1T,
                       const float* __restrict__ b1, const float* __restrict__ W2,
                       const float* __restrict__ b2, float* __restrict__ out)
{
  __shared__ float hrow[1024];
  __shared__ float part[64][5];
  __shared__ float h1[64];
  __shared__ float logit[10];
  int r = blockIdx.x, tid = threadIdx.x;
  for (int i = tid; i < 1024; i += 256) {
    float v = (float)hbuf[(size_t)r * HH + i];
    hrow[i] = v > 0.f ? v : 0.f;
  }
  __syncthreads();
  int n = tid & 63, q = tid >> 6;
  float s = 0.f;
  for (int i = 0; i < 256; ++i) s += hrow[q * 256 + i] * W1T[(q * 256 + i) * 64 + n];
  part[n][q] = s;
  __syncthreads();
  if (tid < 64) {
    float v = part[tid][0] + part[tid][1] + part[tid][2] + part[tid][3] + b1[tid];
    h1[tid] = v > 0.f ? v : 0.f;
  }
  __syncthreads();
  if (tid < 10) {
    float s2 = b2[tid];
    for (int k = 0; k < 64; ++k) s2 += h1[k] * W2[tid * 64 + k];
    logit[tid] = s2;
  }
  __syncthreads();
  if (tid < 10) {
    float m = logit[0];
    for (int i = 1; i < 10; ++i) m = fmaxf(m, logit[i]);
    float sum = 0.f;
    for (int i = 0; i < 10; ++i) sum += __expf(logit[i] - m);
    out[r * 10 + tid] = __expf(logit[tid] - m) / sum;
  }
}

extern "C" void kernel_launch(void* const* d_in, const int* in_sizes, int n_in,
                              void* d_out, int out_size, void* d_ws, size_t ws_size,
                              hipStream_t stream) {
  const float* x   = (const float*)d_in[0];
  const float* Wfx = (const float*)d_in[1];
  const float* Wfh = (const float*)d_in[2];
  const float* bf  = (const float*)d_in[3];
  const float* Wix = (const float*)d_in[4];
  const float* Wih = (const float*)d_in[5];
  const float* bi  = (const float*)d_in[6];
  const float* Wox = (const float*)d_in[7];
  const float* Woh = (const float*)d_in[8];
  const float* bo  = (const float*)d_in[9];
  const float* Wcx = (const float*)d_in[10];
  const float* Wch = (const float*)d_in[11];
  const float* bc  = (const float*)d_in[12];
  const float* W1  = (const float*)d_in[13];
  const float* b1  = (const float*)d_in[14];
  const float* W2  = (const float*)d_in[15];
  const float* b2  = (const float*)d_in[16];
  (void)in_sizes; (void)n_in; (void)out_size;

  char* ws = (char*)d_ws;
  h16* Wx = (h16*)(ws + WX_OFF);
  h16* Wh = (h16*)(ws + WH_OFF);
  float* bias = (float*)(ws + BIAS_OFF);
  float* W1T = (float*)(ws + W1T_OFF);
  h16* hbuf = (h16*)(ws + HBUF_OFF);
  unsigned int* arr = (unsigned int*)(ws + ARR_OFF);
  h16* xh = (h16*)(ws + XH_OFF);
  const int use_xh = (ws_size >= XH_END) ? 1 : 0;

  hipMemsetAsync(arr, 0, 4096, stream);
  k_prep<<<4096, 256, 0, stream>>>(Wfx, Wfh, bf, Wix, Wih, bi, Wox, Woh, bo, Wcx, Wch, bc, W1,
                                   Wx, Wh, bias, W1T);
  if (use_xh) k_castx<<<8192, 256, 0, stream>>>(x, xh);

  (void)hipFuncSetAttribute(reinterpret_cast<const void*>(&k_lstm<1>),
                            hipFuncAttributeMaxDynamicSharedMemorySize, SMEM_BYTES);
  (void)hipFuncSetAttribute(reinterpret_cast<const void*>(&k_lstm<0>),
                            hipFuncAttributeMaxDynamicSharedMemorySize, SMEM_BYTES);
  if (use_xh)
    k_lstm<1><<<256, 512, SMEM_BYTES, stream>>>(x, xh, Wx, Wh, bias, hbuf, arr);
  else
    k_lstm<0><<<256, 512, SMEM_BYTES, stream>>>(x, xh, Wx, Wh, bias, hbuf, arr);

  // h(T-1) lives in parity buffer (TT-1)&1 == 1
  k_head<<<256, 256, 0, stream>>>(hbuf + HSTRIDE, W1T, b1, W2, b2, (float*)d_out);
}

// Round 3
// 2875.574 us; speedup vs baseline: 1.4621x; 1.1101x over previous
//
#include <hip/hip_runtime.h>

#define BB 256
#define TT 256
#define II 512
#define HH 1024

typedef _Float16 h16;
typedef __attribute__((ext_vector_type(4))) _Float16 h16x4;
typedef __attribute__((ext_vector_type(8))) _Float16 h16x8;
typedef __attribute__((ext_vector_type(4))) float f32x4;
typedef __attribute__((ext_vector_type(2))) unsigned int u32x2;
typedef __attribute__((ext_vector_type(4))) unsigned int u32x4;

#define KPADH 1032                 // h16 elems per Abuf row (1024 + 8 pad) = 2064 B
#define PRE_OFF 66048              // 32 * 1032 * 2
#define PRESTRIDE 34               // f32 per Pre row (32 + 2 pad): 2-way banks, 8B aligned
#define PRESLAB (32 * PRESTRIDE)   // 1088 f32 per slab
#define SMEM_BYTES 100864          // 66048 + 8*1088*4

// workspace layout (bytes) — unchanged
#define WX_OFF   0UL
#define WH_OFF   4194304UL
#define BIAS_OFF 12582912UL
#define W1T_OFF  12599296UL
#define HBUF_OFF 12861440UL
#define ARR_OFF  13910016UL
#define XH_OFF   13914112UL
#define XH_END   81022976UL

#define HSTRIDE (BB * HH)

__device__ __forceinline__ float sigm(float x) { return 1.0f / (1.0f + __expf(-x)); }
__device__ __forceinline__ float tanh_(float x) { float e = __expf(2.0f * x); return 1.0f - 2.0f / (e + 1.0f); }

// ---------------- prep: cast/pack weights ----------------
__global__ void k_prep(const float* __restrict__ Wfx, const float* __restrict__ Wfh, const float* __restrict__ bf,
                       const float* __restrict__ Wix, const float* __restrict__ Wih, const float* __restrict__ bi,
                       const float* __restrict__ Wox, const float* __restrict__ Woh, const float* __restrict__ bo,
                       const float* __restrict__ Wcx, const float* __restrict__ Wch, const float* __restrict__ bc,
                       const float* __restrict__ W1,
                       h16* __restrict__ Wx, h16* __restrict__ Wh, float* __restrict__ bias, float* __restrict__ W1T)
{
  const long NWX = 4096L * 512, NWH = 4096L * 1024, NB = 4096, NW1 = 1024L * 64;
  const long total = NWX + NWH + NB + NW1;
  for (long id = blockIdx.x * 256L + threadIdx.x; id < total; id += gridDim.x * 256L) {
    if (id < NWX) {
      long n = id >> 9, k = id & 511;
      long g = n >> 10, j = n & 1023;
      const float* s = (g == 0) ? Wfx : (g == 1) ? Wix : (g == 2) ? Wox : Wcx;
      Wx[id] = (h16)s[j * II + k];
    } else if (id < NWX + NWH) {
      long i2 = id - NWX;
      long n = i2 >> 10, k = i2 & 1023;
      long g = n >> 10, j = n & 1023;
      const float* s = (g == 0) ? Wfh : (g == 1) ? Wih : (g == 2) ? Woh : Wch;
      Wh[i2] = (h16)s[j * HH + k];
    } else if (id < NWX + NWH + NB) {
      long n = id - NWX - NWH;
      long g = n >> 10, j = n & 1023;
      const float* s = (g == 0) ? bf : (g == 1) ? bi : (g == 2) ? bo : bc;
      bias[n] = s[j];
    } else {
      long i2 = id - NWX - NWH - NB;
      long k = i2 >> 6, n = i2 & 63;
      W1T[i2] = W1[n * HH + k];
    }
  }
}

// ---------------- prep: cast x to fp16 ----------------
__global__ void k_castx(const float* __restrict__ x, h16* __restrict__ xh) {
  const long n = (long)BB * TT * II;
  for (long i = (blockIdx.x * 256L + threadIdx.x) * 4; i < n; i += gridDim.x * 1024L) {
    float4 v = *(const float4*)(x + i);
    h16x4 o = {(h16)v.x, (h16)v.y, (h16)v.z, (h16)v.w};
    *(h16x4*)(xh + i) = o;
  }
}

// ---------------- persistent LSTM kernel ----------------
// 8 groups x 32 batch rows; 32 WGs per group; WG = 32 rows x 32 cols x 4 gates.
// 8 waves = 4 gates x 2 K-halves (split-K); Wh register-resident (128 VGPR/wave).
// Per-step schedule (2 barriers):
//   xA (kk 0-3, h-independent: absorbs producer skew)
//   poll (ALL waves independently; 256 packed u16 slots, 1 dwordx2/lane)
//   issue 8 coherent staging loads of h(t-1)
//   xB (kk 4-7: hides staging flight)
//   vmcnt(0); staging -> Abuf; barrier(1)
//   h-GEMM (ds_read + MFMA, B in registers)
//   Pre partials -> LDS; barrier(2)
//   elementwise (c in regs); coherent h-store; per-wave vmcnt(0) drain;
//   per-wave u16 publish (lane 0)
// Hazards: barrier(1) covers Abuf write(t)/read(t); barrier(2) covers Pre
// write/read AND orders h-GEMM-read(t) before any wave's Abuf write(t+1)
// (a wave stage-writes t+1 only after passing barrier(2)(t)). Pre read(t) vs
// write(t+1) is covered by barrier(1)(t+1). hbuf parity WAR: h-store(t) to
// buf[t&1] happens after poll(t) which requires every wave's publish(t-1→t),
// which orders after that wave's staging reads of buf[t&1] at step t-1.
template <int USE_XH>
__global__ __launch_bounds__(512, 1) void k_lstm(
    const float* __restrict__ x32, const h16* __restrict__ x16,
    const h16* __restrict__ Wx, const h16* __restrict__ Wh,
    const float* __restrict__ bias,
    h16* __restrict__ hbuf, unsigned short* __restrict__ arr)
{
  extern __shared__ char smem[];
  h16* Abuf = (h16*)smem;                 // [32][KPADH] fp16
  float* Pre = (float*)(smem + PRE_OFF);  // [8][32][PRESTRIDE] f32, slab = g*2+kh

  const int tid = threadIdx.x;
  const int wid = tid >> 6;   // 0..7
  const int lane = tid & 63;
  const int lm = lane & 15;   // MFMA row/col within 16
  const int lq = lane >> 4;   // k-quad

  const int bx = blockIdx.x;
  const int group = bx >> 5;      // 0..7 (32 batch rows each)
  const int nslice = bx & 31;     // col slice 0..31 (nslice&7 == XCD)
  const int r0 = group * 32;
  const int hc0 = nslice * 32;

  const int g = wid >> 1;          // gate 0..3
  const int kh = wid & 1;          // K-half 0..1

  const int ng0 = g * HH + hc0 + lm;        // packed-weight row, col-tile 0
  const int ng1 = ng0 + 16;                 // col-tile 1
  const float bs0 = (kh == 0) ? bias[ng0] : 0.f;
  const float bs1 = (kh == 0) ? bias[ng1] : 0.f;

  const h16* WxB0 = Wx + (size_t)ng0 * II + kh * 256 + lq * 8;
  const h16* WxB1 = Wx + (size_t)ng1 * II + kh * 256 + lq * 8;

  // ---- Wh fragments into registers ONCE (2 col-tiles x 16 kk = 128 VGPRs) ----
  h16x8 wh0[16], wh1[16];
  {
    const h16* p0 = Wh + (size_t)ng0 * HH + kh * 512 + lq * 8;
    const h16* p1 = Wh + (size_t)ng1 * HH + kh * 512 + lq * 8;
#pragma unroll
    for (int kk = 0; kk < 16; ++kk) {
      wh0[kk] = *(const h16x8*)(p0 + kk * 32);
      wh1[kk] = *(const h16x8*)(p1 + kk * 32);
    }
  }

  const size_t TI = (size_t)TT * II;
  const float* xr32_0 = x32 + (size_t)(r0 + lm) * TI + kh * 256 + lq * 8;
  const float* xr32_1 = xr32_0 + 16 * TI;
  const h16* xr16_0 = x16 + (size_t)(r0 + lm) * TI + kh * 256 + lq * 8;
  const h16* xr16_1 = xr16_0 + 16 * TI;

  const int aB0 = lm * KPADH + kh * 512 + lq * 8;          // rt=0 rows
  const int aB1 = (16 + lm) * KPADH + kh * 512 + lq * 8;   // rt=1 rows

  const int urow = tid >> 4;        // 0..31
  const int ucolp = (tid & 15) * 2; // 0,2,..,30
  float cst[2] = {0.f, 0.f};

  // 256 u16 slots per group: one per (nslice, wave)
  unsigned short* slots = arr + group * 256;
  unsigned short* myslot = slots + nslice * 8 + wid;
  const unsigned short* pollp = slots + lane * 4;   // 4 slots/lane via dwordx2

  for (int t = 0; t < TT; ++t) {
    f32x4 a00 = {bs0, bs0, bs0, bs0};
    f32x4 a01 = {bs1, bs1, bs1, bs1};
    f32x4 a10 = a00;
    f32x4 a11 = a01;

    const size_t tOff = (size_t)t * II;

    // ---- xA: kk 0..3 (h-independent; absorbs producer skew) ----
#pragma unroll
    for (int kk = 0; kk < 4; ++kk) {
      h16x8 xa0, xa1;
      if (USE_XH) {
        xa0 = *(const h16x8*)(xr16_0 + tOff + kk * 32);
        xa1 = *(const h16x8*)(xr16_1 + tOff + kk * 32);
      } else {
        const float* p0 = xr32_0 + tOff + kk * 32;
        const float* p1 = xr32_1 + tOff + kk * 32;
        float4 u0 = *(const float4*)(p0), v0 = *(const float4*)(p0 + 4);
        float4 u1 = *(const float4*)(p1), v1 = *(const float4*)(p1 + 4);
        xa0 = (h16x8){(h16)u0.x, (h16)u0.y, (h16)u0.z, (h16)u0.w, (h16)v0.x, (h16)v0.y, (h16)v0.z, (h16)v0.w};
        xa1 = (h16x8){(h16)u1.x, (h16)u1.y, (h16)u1.z, (h16)u1.w, (h16)v1.x, (h16)v1.y, (h16)v1.z, (h16)v1.w};
      }
      h16x8 xb0 = *(const h16x8*)(WxB0 + kk * 32);
      h16x8 xb1 = *(const h16x8*)(WxB1 + kk * 32);
      a00 = __builtin_amdgcn_mfma_f32_16x16x32_f16(xa0, xb0, a00, 0, 0, 0);
      a01 = __builtin_amdgcn_mfma_f32_16x16x32_f16(xa0, xb1, a01, 0, 0, 0);
      a10 = __builtin_amdgcn_mfma_f32_16x16x32_f16(xa1, xb0, a10, 0, 0, 0);
      a11 = __builtin_amdgcn_mfma_f32_16x16x32_f16(xa1, xb1, a11, 0, 0, 0);
    }

    u32x4 stg[8];
    if (t > 0) {
      // ---- poll: ALL waves, no barrier; 4 packed u16 slots per lane ----
      {
        u32x2 vv;
        unsigned int mn;
        do {
          asm volatile("global_load_dwordx2 %0, %1, off sc0 sc1\n\t"
                       "s_waitcnt vmcnt(0)"
                       : "=v"(vv) : "v"(pollp) : "memory");
          unsigned int m0 = vv.x & 0xffffu, m1 = vv.x >> 16;
          unsigned int m2 = vv.y & 0xffffu, m3 = vv.y >> 16;
          mn = min(min(m0, m1), min(m2, m3));
        } while (__any(mn < (unsigned int)t));
      }
      // ---- issue staging of h(t-1) (IC-coherent); completes under xB ----
      {
        const h16* hs = hbuf + (size_t)((t - 1) & 1) * HSTRIDE + (size_t)r0 * HH;
#pragma unroll
        for (int j = 0; j < 8; ++j) {
          int c = tid + j * 512;            // 0..4095 granules of 16B
          const h16* p = hs + (size_t)(c >> 7) * HH + (c & 127) * 8;
          asm volatile("global_load_dwordx4 %0, %1, off sc0 sc1"
                       : "=v"(stg[j]) : "v"(p) : "memory");
        }
      }
    }

    // ---- xB: kk 4..7 (staging loads fly underneath) ----
#pragma unroll
    for (int kk = 4; kk < 8; ++kk) {
      h16x8 xa0, xa1;
      if (USE_XH) {
        xa0 = *(const h16x8*)(xr16_0 + tOff + kk * 32);
        xa1 = *(const h16x8*)(xr16_1 + tOff + kk * 32);
      } else {
        const float* p0 = xr32_0 + tOff + kk * 32;
        const float* p1 = xr32_1 + tOff + kk * 32;
        float4 u0 = *(const float4*)(p0), v0 = *(const float4*)(p0 + 4);
        float4 u1 = *(const float4*)(p1), v1 = *(const float4*)(p1 + 4);
        xa0 = (h16x8){(h16)u0.x, (h16)u0.y, (h16)u0.z, (h16)u0.w, (h16)v0.x, (h16)v0.y, (h16)v0.z, (h16)v0.w};
        xa1 = (h16x8){(h16)u1.x, (h16)u1.y, (h16)u1.z, (h16)u1.w, (h16)v1.x, (h16)v1.y, (h16)v1.z, (h16)v1.w};
      }
      h16x8 xb0 = *(const h16x8*)(WxB0 + kk * 32);
      h16x8 xb1 = *(const h16x8*)(WxB1 + kk * 32);
      a00 = __builtin_amdgcn_mfma_f32_16x16x32_f16(xa0, xb0, a00, 0, 0, 0);
      a01 = __builtin_amdgcn_mfma_f32_16x16x32_f16(xa0, xb1, a01, 0, 0, 0);
      a10 = __builtin_amdgcn_mfma_f32_16x16x32_f16(xa1, xb0, a10, 0, 0, 0);
      a11 = __builtin_amdgcn_mfma_f32_16x16x32_f16(xa1, xb1, a11, 0, 0, 0);
    }

    if (t > 0) {
      // ---- drain staging, unload to LDS (single wait wall) ----
      asm volatile("s_waitcnt vmcnt(0)" ::: "memory");
#pragma unroll
      for (int j = 0; j < 8; ++j) {
        int c = tid + j * 512;
        *(u32x4*)(Abuf + (c >> 7) * KPADH + (c & 127) * 8) = stg[j];
      }
      __syncthreads();   // barrier(1)
      // ---- h-part GEMM, this wave's K-half only (B in registers) ----
#pragma unroll
      for (int kk = 0; kk < 16; ++kk) {
        h16x8 ha0 = *(const h16x8*)(Abuf + aB0 + kk * 32);
        h16x8 ha1 = *(const h16x8*)(Abuf + aB1 + kk * 32);
        a00 = __builtin_amdgcn_mfma_f32_16x16x32_f16(ha0, wh0[kk], a00, 0, 0, 0);
        a01 = __builtin_amdgcn_mfma_f32_16x16x32_f16(ha0, wh1[kk], a01, 0, 0, 0);
        a10 = __builtin_amdgcn_mfma_f32_16x16x32_f16(ha1, wh0[kk], a10, 0, 0, 0);
        a11 = __builtin_amdgcn_mfma_f32_16x16x32_f16(ha1, wh1[kk], a11, 0, 0, 0);
      }
    }

    // ---- partial preacts -> LDS (cross-wave gate + split-K exchange) ----
    {
      float* Pg = Pre + (size_t)(g * 2 + kh) * PRESLAB;
#pragma unroll
      for (int i = 0; i < 4; ++i) {
        int rA = lq * 4 + i;
        Pg[rA * PRESTRIDE + lm]              = a00[i];
        Pg[rA * PRESTRIDE + 16 + lm]         = a01[i];
        Pg[(16 + rA) * PRESTRIDE + lm]       = a10[i];
        Pg[(16 + rA) * PRESTRIDE + 16 + lm]  = a11[i];
      }
    }
    __syncthreads();   // barrier(2)
    // ---- elementwise c/h update (c persistent in regs), write h to buf[t&1] ----
    {
      const float* Pq = Pre + urow * PRESTRIDE + ucolp;   // 8B aligned
      float2 q0 = *(const float2*)(Pq + 0 * PRESLAB);
      float2 q1 = *(const float2*)(Pq + 1 * PRESLAB);
      float2 q2 = *(const float2*)(Pq + 2 * PRESLAB);
      float2 q3 = *(const float2*)(Pq + 3 * PRESLAB);
      float2 q4 = *(const float2*)(Pq + 4 * PRESLAB);
      float2 q5 = *(const float2*)(Pq + 5 * PRESLAB);
      float2 q6 = *(const float2*)(Pq + 6 * PRESLAB);
      float2 q7 = *(const float2*)(Pq + 7 * PRESLAB);
      float hv[2];
      {
        float fp = q0.x + q1.x, ip = q2.x + q3.x, op = q4.x + q5.x, cp = q6.x + q7.x;
        float c2 = sigm(fp) * cst[0] + sigm(ip) * tanh_(cp);
        cst[0] = c2;
        hv[0] = sigm(op) * tanh_(c2);
      }
      {
        float fp = q0.y + q1.y, ip = q2.y + q3.y, op = q4.y + q5.y, cp = q6.y + q7.y;
        float c2 = sigm(fp) * cst[1] + sigm(ip) * tanh_(cp);
        cst[1] = c2;
        hv[1] = sigm(op) * tanh_(c2);
      }
      union { h16 h[2]; unsigned int u; } pk;
      pk.h[0] = (h16)hv[0]; pk.h[1] = (h16)hv[1];
      const h16* hp = hbuf + (size_t)(t & 1) * HSTRIDE + (size_t)(r0 + urow) * HH + hc0 + ucolp;
      asm volatile("global_store_dword %0, %1, off sc0 sc1"
                   :: "v"(hp), "v"(pk.u) : "memory");
    }
    // ---- per-wave drain + publish (no barrier) ----
    asm volatile("s_waitcnt vmcnt(0)" ::: "memory");   // this wave's h stores at IC
    if (lane == 0) {
      unsigned int val = (unsigned int)(t + 1);
      asm volatile("global_store_short %0, %1, off sc0 sc1"
                   :: "v"(myslot), "v"(val) : "memory");
    }
  }
}

// ---------------- head: relu -> [64] relu -> [10] softmax ----------------
__global__ void k_head(const h16* __restrict__ hbuf, const float* __restrict__ W1T,
                       const float* __restrict__ b1, const float* __restrict__ W2,
                       const float* __restrict__ b2, float* __restrict__ out)
{
  __shared__ float hrow[1024];
  __shared__ float part[64][5];
  __shared__ float h1[64];
  __shared__ float logit[10];
  int r = blockIdx.x, tid = threadIdx.x;
  for (int i = tid; i < 1024; i += 256) {
    float v = (float)hbuf[(size_t)r * HH + i];
    hrow[i] = v > 0.f ? v : 0.f;
  }
  __syncthreads();
  int n = tid & 63, q = tid >> 6;
  float s = 0.f;
  for (int i = 0; i < 256; ++i) s += hrow[q * 256 + i] * W1T[(q * 256 + i) * 64 + n];
  part[n][q] = s;
  __syncthreads();
  if (tid < 64) {
    float v = part[tid][0] + part[tid][1] + part[tid][2] + part[tid][3] + b1[tid];
    h1[tid] = v > 0.f ? v : 0.f;
  }
  __syncthreads();
  if (tid < 10) {
    float s2 = b2[tid];
    for (int k = 0; k < 64; ++k) s2 += h1[k] * W2[tid * 64 + k];
    logit[tid] = s2;
  }
  __syncthreads();
  if (tid < 10) {
    float m = logit[0];
    for (int i = 1; i < 10; ++i) m = fmaxf(m, logit[i]);
    float sum = 0.f;
    for (int i = 0; i < 10; ++i) sum += __expf(logit[i] - m);
    out[r * 10 + tid] = __expf(logit[tid] - m) / sum;
  }
}

extern "C" void kernel_launch(void* const* d_in, const int* in_sizes, int n_in,
                              void* d_out, int out_size, void* d_ws, size_t ws_size,
                              hipStream_t stream) {
  const float* x   = (const float*)d_in[0];
  const float* Wfx = (const float*)d_in[1];
  const float* Wfh = (const float*)d_in[2];
  const float* bf  = (const float*)d_in[3];
  const float* Wix = (const float*)d_in[4];
  const float* Wih = (const float*)d_in[5];
  const float* bi  = (const float*)d_in[6];
  const float* Wox = (const float*)d_in[7];
  const float* Woh = (const float*)d_in[8];
  const float* bo  = (const float*)d_in[9];
  const float* Wcx = (const float*)d_in[10];
  const float* Wch = (const float*)d_in[11];
  const float* bc  = (const float*)d_in[12];
  const float* W1  = (const float*)d_in[13];
  const float* b1  = (const float*)d_in[14];
  const float* W2  = (const float*)d_in[15];
  const float* b2  = (const float*)d_in[16];
  (void)in_sizes; (void)n_in; (void)out_size;

  char* ws = (char*)d_ws;
  h16* Wx = (h16*)(ws + WX_OFF);
  h16* Wh = (h16*)(ws + WH_OFF);
  float* bias = (float*)(ws + BIAS_OFF);
  float* W1T = (float*)(ws + W1T_OFF);
  h16* hbuf = (h16*)(ws + HBUF_OFF);
  unsigned short* arr = (unsigned short*)(ws + ARR_OFF);
  h16* xh = (h16*)(ws + XH_OFF);
  const int use_xh = (ws_size >= XH_END) ? 1 : 0;

  hipMemsetAsync(arr, 0, 4096, stream);   // 8 groups x 256 u16 slots
  k_prep<<<4096, 256, 0, stream>>>(Wfx, Wfh, bf, Wix, Wih, bi, Wox, Woh, bo, Wcx, Wch, bc, W1,
                                   Wx, Wh, bias, W1T);
  if (use_xh) k_castx<<<8192, 256, 0, stream>>>(x, xh);

  (void)hipFuncSetAttribute(reinterpret_cast<const void*>(&k_lstm<1>),
                            hipFuncAttributeMaxDynamicSharedMemorySize, SMEM_BYTES);
  (void)hipFuncSetAttribute(reinterpret_cast<const void*>(&k_lstm<0>),
                            hipFuncAttributeMaxDynamicSharedMemorySize, SMEM_BYTES);
  if (use_xh)
    k_lstm<1><<<256, 512, SMEM_BYTES, stream>>>(x, xh, Wx, Wh, bias, hbuf, arr);
  else
    k_lstm<0><<<256, 512, SMEM_BYTES, stream>>>(x, xh, Wx, Wh, bias, hbuf, arr);

  // h(T-1) lives in parity buffer (TT-1)&1 == 1
  k_head<<<256, 256, 0, stream>>>(hbuf + HSTRIDE, W1T, b1, W2, b2, (float*)d_out);
}

// Round 7
// 2867.679 us; speedup vs baseline: 1.4661x; 1.0028x over previous
//
#include <hip/hip_runtime.h>

#define BB 256
#define TT 256
#define II 512
#define HH 1024

typedef _Float16 h16;
typedef __attribute__((ext_vector_type(4))) _Float16 h16x4;
typedef __attribute__((ext_vector_type(8))) _Float16 h16x8;
typedef __attribute__((ext_vector_type(4))) float f32x4;
typedef __attribute__((ext_vector_type(2))) unsigned int u32x2;
typedef __attribute__((ext_vector_type(4))) unsigned int u32x4;

#define KPADH 1032                 // h16 elems per Abuf row (1024 + 8 pad) = 2064 B
#define PRE_OFF 66048              // 32 * 1032 * 2
#define PRESTRIDE 34               // f32 per Pre row (32 + 2 pad): 2-way banks, 8B aligned
#define PRESLAB (32 * PRESTRIDE)   // 1088 f32 per slab
#define SMEM_BYTES 100864          // 66048 + 8*1088*4

// workspace layout (bytes) — unchanged
#define WX_OFF   0UL
#define WH_OFF   4194304UL
#define BIAS_OFF 12582912UL
#define W1T_OFF  12599296UL
#define HBUF_OFF 12861440UL
#define ARR_OFF  13910016UL
#define XH_OFF   13914112UL
#define XH_END   81022976UL

#define HSTRIDE (BB * HH)

__device__ __forceinline__ float sigm(float x) { return 1.0f / (1.0f + __expf(-x)); }
__device__ __forceinline__ float tanh_(float x) { float e = __expf(2.0f * x); return 1.0f - 2.0f / (e + 1.0f); }

// ---------------- prep: cast/pack weights ----------------
__global__ void k_prep(const float* __restrict__ Wfx, const float* __restrict__ Wfh, const float* __restrict__ bf,
                       const float* __restrict__ Wix, const float* __restrict__ Wih, const float* __restrict__ bi,
                       const float* __restrict__ Wox, const float* __restrict__ Woh, const float* __restrict__ bo,
                       const float* __restrict__ Wcx, const float* __restrict__ Wch, const float* __restrict__ bc,
                       const float* __restrict__ W1,
                       h16* __restrict__ Wx, h16* __restrict__ Wh, float* __restrict__ bias, float* __restrict__ W1T)
{
  const long NWX = 4096L * 512, NWH = 4096L * 1024, NB = 4096, NW1 = 1024L * 64;
  const long total = NWX + NWH + NB + NW1;
  for (long id = blockIdx.x * 256L + threadIdx.x; id < total; id += gridDim.x * 256L) {
    if (id < NWX) {
      long n = id >> 9, k = id & 511;
      long g = n >> 10, j = n & 1023;
      const float* s = (g == 0) ? Wfx : (g == 1) ? Wix : (g == 2) ? Wox : Wcx;
      Wx[id] = (h16)s[j * II + k];
    } else if (id < NWX + NWH) {
      long i2 = id - NWX;
      long n = i2 >> 10, k = i2 & 1023;
      long g = n >> 10, j = n & 1023;
      const float* s = (g == 0) ? Wfh : (g == 1) ? Wih : (g == 2) ? Woh : Wch;
      Wh[i2] = (h16)s[j * HH + k];
    } else if (id < NWX + NWH + NB) {
      long n = id - NWX - NWH;
      long g = n >> 10, j = n & 1023;
      const float* s = (g == 0) ? bf : (g == 1) ? bi : (g == 2) ? bo : bc;
      bias[n] = s[j];
    } else {
      long i2 = id - NWX - NWH - NB;
      long k = i2 >> 6, n = i2 & 63;
      W1T[i2] = W1[n * HH + k];
    }
  }
}

// ---------------- prep: cast x to fp16 ----------------
__global__ void k_castx(const float* __restrict__ x, h16* __restrict__ xh) {
  const long n = (long)BB * TT * II;
  for (long i = (blockIdx.x * 256L + threadIdx.x) * 4; i < n; i += gridDim.x * 1024L) {
    float4 v = *(const float4*)(x + i);
    h16x4 o = {(h16)v.x, (h16)v.y, (h16)v.z, (h16)v.w};
    *(h16x4*)(xh + i) = o;
  }
}

// ---------------- persistent LSTM kernel ----------------
// 8 groups x 32 batch rows; 32 WGs per group; WG = 32 rows x 32 cols x 4 gates.
// 8 waves = 4 gates x 2 K-halves (split-K); Wh register-resident (128 VGPR/wave).
// Per-step schedule (2 barriers):
//   xA (kk 0-3, h-independent: absorbs producer skew)
//   poll (ALL waves independently; 256 packed u16 slots, 1 dwordx2/lane)
//   issue 8 coherent staging loads of h(t-1)
//   xB (kk 4-7: hides staging flight)
//   vmcnt(0); staging -> Abuf; barrier(1)
//   h-GEMM (ds_read + MFMA, B in registers)
//   Pre partials -> LDS; barrier(2)
//   elementwise (c in regs); coherent h-store; per-wave vmcnt(0) drain;
//   per-wave u16 publish (lane 0)
// Hazards: barrier(1) covers Abuf write(t)/read(t); barrier(2) covers Pre
// write/read AND orders h-GEMM-read(t) before any wave's Abuf write(t+1)
// (a wave stage-writes t+1 only after passing barrier(2)(t)). Pre read(t) vs
// write(t+1) is covered by barrier(1)(t+1). hbuf parity WAR: h-store(t) to
// buf[t&1] happens after poll(t) which requires every wave's publish(t-1→t),
// which orders after that wave's staging reads of buf[t&1] at step t-1.
// All inter-WG sync ops are system-scope (sc0 sc1) — the ONLY protocol that
// has passed on hardware; sc0-only (L2-scope) variants hang (3/3 failures,
// suspected: sc0 loads may not bypass L1 on gfx950 -> stale poll spin).
template <int USE_XH>
__global__ __launch_bounds__(512, 1) void k_lstm(
    const float* __restrict__ x32, const h16* __restrict__ x16,
    const h16* __restrict__ Wx, const h16* __restrict__ Wh,
    const float* __restrict__ bias,
    h16* __restrict__ hbuf, unsigned short* __restrict__ arr)
{
  extern __shared__ char smem[];
  h16* Abuf = (h16*)smem;                 // [32][KPADH] fp16
  float* Pre = (float*)(smem + PRE_OFF);  // [8][32][PRESTRIDE] f32, slab = g*2+kh

  const int tid = threadIdx.x;
  const int wid = tid >> 6;   // 0..7
  const int lane = tid & 63;
  const int lm = lane & 15;   // MFMA row/col within 16
  const int lq = lane >> 4;   // k-quad

  const int bx = blockIdx.x;
  const int group = bx >> 5;      // 0..7 (32 batch rows each)
  const int nslice = bx & 31;     // col slice 0..31 (nslice&7 == XCD)
  const int r0 = group * 32;
  const int hc0 = nslice * 32;

  const int g = wid >> 1;          // gate 0..3
  const int kh = wid & 1;          // K-half 0..1

  const int ng0 = g * HH + hc0 + lm;        // packed-weight row, col-tile 0
  const int ng1 = ng0 + 16;                 // col-tile 1
  const float bs0 = (kh == 0) ? bias[ng0] : 0.f;
  const float bs1 = (kh == 0) ? bias[ng1] : 0.f;

  const h16* WxB0 = Wx + (size_t)ng0 * II + kh * 256 + lq * 8;
  const h16* WxB1 = Wx + (size_t)ng1 * II + kh * 256 + lq * 8;

  // ---- Wh fragments into registers ONCE (2 col-tiles x 16 kk = 128 VGPRs) ----
  h16x8 wh0[16], wh1[16];
  {
    const h16* p0 = Wh + (size_t)ng0 * HH + kh * 512 + lq * 8;
    const h16* p1 = Wh + (size_t)ng1 * HH + kh * 512 + lq * 8;
#pragma unroll
    for (int kk = 0; kk < 16; ++kk) {
      wh0[kk] = *(const h16x8*)(p0 + kk * 32);
      wh1[kk] = *(const h16x8*)(p1 + kk * 32);
    }
  }

  const size_t TI = (size_t)TT * II;
  const float* xr32_0 = x32 + (size_t)(r0 + lm) * TI + kh * 256 + lq * 8;
  const float* xr32_1 = xr32_0 + 16 * TI;
  const h16* xr16_0 = x16 + (size_t)(r0 + lm) * TI + kh * 256 + lq * 8;
  const h16* xr16_1 = xr16_0 + 16 * TI;

  const int aB0 = lm * KPADH + kh * 512 + lq * 8;          // rt=0 rows
  const int aB1 = (16 + lm) * KPADH + kh * 512 + lq * 8;   // rt=1 rows

  const int urow = tid >> 4;        // 0..31
  const int ucolp = (tid & 15) * 2; // 0,2,..,30
  float cst[2] = {0.f, 0.f};

  // 256 u16 slots per group: one per (nslice, wave)
  unsigned short* slots = arr + group * 256;
  unsigned short* myslot = slots + nslice * 8 + wid;
  const unsigned short* pollp = slots + lane * 4;   // 4 slots/lane via dwordx2

  for (int t = 0; t < TT; ++t) {
    f32x4 a00 = {bs0, bs0, bs0, bs0};
    f32x4 a01 = {bs1, bs1, bs1, bs1};
    f32x4 a10 = a00;
    f32x4 a11 = a01;

    const size_t tOff = (size_t)t * II;

    // ---- xA: kk 0..3 (h-independent; absorbs producer skew) ----
#pragma unroll
    for (int kk = 0; kk < 4; ++kk) {
      h16x8 xa0, xa1;
      if (USE_XH) {
        xa0 = *(const h16x8*)(xr16_0 + tOff + kk * 32);
        xa1 = *(const h16x8*)(xr16_1 + tOff + kk * 32);
      } else {
        const float* p0 = xr32_0 + tOff + kk * 32;
        const float* p1 = xr32_1 + tOff + kk * 32;
        float4 u0 = *(const float4*)(p0), v0 = *(const float4*)(p0 + 4);
        float4 u1 = *(const float4*)(p1), v1 = *(const float4*)(p1 + 4);
        xa0 = (h16x8){(h16)u0.x, (h16)u0.y, (h16)u0.z, (h16)u0.w, (h16)v0.x, (h16)v0.y, (h16)v0.z, (h16)v0.w};
        xa1 = (h16x8){(h16)u1.x, (h16)u1.y, (h16)u1.z, (h16)u1.w, (h16)v1.x, (h16)v1.y, (h16)v1.z, (h16)v1.w};
      }
      h16x8 xb0 = *(const h16x8*)(WxB0 + kk * 32);
      h16x8 xb1 = *(const h16x8*)(WxB1 + kk * 32);
      a00 = __builtin_amdgcn_mfma_f32_16x16x32_f16(xa0, xb0, a00, 0, 0, 0);
      a01 = __builtin_amdgcn_mfma_f32_16x16x32_f16(xa0, xb1, a01, 0, 0, 0);
      a10 = __builtin_amdgcn_mfma_f32_16x16x32_f16(xa1, xb0, a10, 0, 0, 0);
      a11 = __builtin_amdgcn_mfma_f32_16x16x32_f16(xa1, xb1, a11, 0, 0, 0);
    }

    u32x4 stg[8];
    if (t > 0) {
      // ---- poll: ALL waves, no barrier; 4 packed u16 slots per lane ----
      {
        u32x2 vv;
        unsigned int mn;
        do {
          asm volatile("global_load_dwordx2 %0, %1, off sc0 sc1\n\t"
                       "s_waitcnt vmcnt(0)"
                       : "=v"(vv) : "v"(pollp) : "memory");
          unsigned int m0 = vv.x & 0xffffu, m1 = vv.x >> 16;
          unsigned int m2 = vv.y & 0xffffu, m3 = vv.y >> 16;
          mn = min(min(m0, m1), min(m2, m3));
        } while (__any(mn < (unsigned int)t));
      }
      // ---- issue staging of h(t-1) (IC-coherent); completes under xB ----
      {
        const h16* hs = hbuf + (size_t)((t - 1) & 1) * HSTRIDE + (size_t)r0 * HH;
#pragma unroll
        for (int j = 0; j < 8; ++j) {
          int c = tid + j * 512;            // 0..4095 granules of 16B
          const h16* p = hs + (size_t)(c >> 7) * HH + (c & 127) * 8;
          asm volatile("global_load_dwordx4 %0, %1, off sc0 sc1"
                       : "=v"(stg[j]) : "v"(p) : "memory");
        }
      }
    }

    // ---- xB: kk 4..7 (staging loads fly underneath) ----
#pragma unroll
    for (int kk = 4; kk < 8; ++kk) {
      h16x8 xa0, xa1;
      if (USE_XH) {
        xa0 = *(const h16x8*)(xr16_0 + tOff + kk * 32);
        xa1 = *(const h16x8*)(xr16_1 + tOff + kk * 32);
      } else {
        const float* p0 = xr32_0 + tOff + kk * 32;
        const float* p1 = xr32_1 + tOff + kk * 32;
        float4 u0 = *(const float4*)(p0), v0 = *(const float4*)(p0 + 4);
        float4 u1 = *(const float4*)(p1), v1 = *(const float4*)(p1 + 4);
        xa0 = (h16x8){(h16)u0.x, (h16)u0.y, (h16)u0.z, (h16)u0.w, (h16)v0.x, (h16)v0.y, (h16)v0.z, (h16)v0.w};
        xa1 = (h16x8){(h16)u1.x, (h16)u1.y, (h16)u1.z, (h16)u1.w, (h16)v1.x, (h16)v1.y, (h16)v1.z, (h16)v1.w};
      }
      h16x8 xb0 = *(const h16x8*)(WxB0 + kk * 32);
      h16x8 xb1 = *(const h16x8*)(WxB1 + kk * 32);
      a00 = __builtin_amdgcn_mfma_f32_16x16x32_f16(xa0, xb0, a00, 0, 0, 0);
      a01 = __builtin_amdgcn_mfma_f32_16x16x32_f16(xa0, xb1, a01, 0, 0, 0);
      a10 = __builtin_amdgcn_mfma_f32_16x16x32_f16(xa1, xb0, a10, 0, 0, 0);
      a11 = __builtin_amdgcn_mfma_f32_16x16x32_f16(xa1, xb1, a11, 0, 0, 0);
    }

    if (t > 0) {
      // ---- drain staging, unload to LDS (single wait wall) ----
      asm volatile("s_waitcnt vmcnt(0)" ::: "memory");
#pragma unroll
      for (int j = 0; j < 8; ++j) {
        int c = tid + j * 512;
        *(u32x4*)(Abuf + (c >> 7) * KPADH + (c & 127) * 8) = stg[j];
      }
      __syncthreads();   // barrier(1)
      // ---- h-part GEMM, this wave's K-half only (B in registers) ----
#pragma unroll
      for (int kk = 0; kk < 16; ++kk) {
        h16x8 ha0 = *(const h16x8*)(Abuf + aB0 + kk * 32);
        h16x8 ha1 = *(const h16x8*)(Abuf + aB1 + kk * 32);
        a00 = __builtin_amdgcn_mfma_f32_16x16x32_f16(ha0, wh0[kk], a00, 0, 0, 0);
        a01 = __builtin_amdgcn_mfma_f32_16x16x32_f16(ha0, wh1[kk], a01, 0, 0, 0);
        a10 = __builtin_amdgcn_mfma_f32_16x16x32_f16(ha1, wh0[kk], a10, 0, 0, 0);
        a11 = __builtin_amdgcn_mfma_f32_16x16x32_f16(ha1, wh1[kk], a11, 0, 0, 0);
      }
    }

    // ---- partial preacts -> LDS (cross-wave gate + split-K exchange) ----
    {
      float* Pg = Pre + (size_t)(g * 2 + kh) * PRESLAB;
#pragma unroll
      for (int i = 0; i < 4; ++i) {
        int rA = lq * 4 + i;
        Pg[rA * PRESTRIDE + lm]              = a00[i];
        Pg[rA * PRESTRIDE + 16 + lm]         = a01[i];
        Pg[(16 + rA) * PRESTRIDE + lm]       = a10[i];
        Pg[(16 + rA) * PRESTRIDE + 16 + lm]  = a11[i];
      }
    }
    __syncthreads();   // barrier(2)
    // ---- elementwise c/h update (c persistent in regs), write h to buf[t&1] ----
    {
      const float* Pq = Pre + urow * PRESTRIDE + ucolp;   // 8B aligned
      float2 q0 = *(const float2*)(Pq + 0 * PRESLAB);
      float2 q1 = *(const float2*)(Pq + 1 * PRESLAB);
      float2 q2 = *(const float2*)(Pq + 2 * PRESLAB);
      float2 q3 = *(const float2*)(Pq + 3 * PRESLAB);
      float2 q4 = *(const float2*)(Pq + 4 * PRESLAB);
      float2 q5 = *(const float2*)(Pq + 5 * PRESLAB);
      float2 q6 = *(const float2*)(Pq + 6 * PRESLAB);
      float2 q7 = *(const float2*)(Pq + 7 * PRESLAB);
      float hv[2];
      {
        float fp = q0.x + q1.x, ip = q2.x + q3.x, op = q4.x + q5.x, cp = q6.x + q7.x;
        float c2 = sigm(fp) * cst[0] + sigm(ip) * tanh_(cp);
        cst[0] = c2;
        hv[0] = sigm(op) * tanh_(c2);
      }
      {
        float fp = q0.y + q1.y, ip = q2.y + q3.y, op = q4.y + q5.y, cp = q6.y + q7.y;
        float c2 = sigm(fp) * cst[1] + sigm(ip) * tanh_(cp);
        cst[1] = c2;
        hv[1] = sigm(op) * tanh_(c2);
      }
      union { h16 h[2]; unsigned int u; } pk;
      pk.h[0] = (h16)hv[0]; pk.h[1] = (h16)hv[1];
      const h16* hp = hbuf + (size_t)(t & 1) * HSTRIDE + (size_t)(r0 + urow) * HH + hc0 + ucolp;
      asm volatile("global_store_dword %0, %1, off sc0 sc1"
                   :: "v"(hp), "v"(pk.u) : "memory");
    }
    // ---- per-wave drain + publish (no barrier) ----
    asm volatile("s_waitcnt vmcnt(0)" ::: "memory");   // this wave's h stores at IC
    if (lane == 0) {
      unsigned int val = (unsigned int)(t + 1);
      asm volatile("global_store_short %0, %1, off sc0 sc1"
                   :: "v"(myslot), "v"(val) : "memory");
    }
  }
}

// ---------------- head: relu -> [64] relu -> [10] softmax ----------------
__global__ void k_head(const h16* __restrict__ hbuf, const float* __restrict__ W1T,
                       const float* __restrict__ b1, const float* __restrict__ W2,
                       const float* __restrict__ b2, float* __restrict__ out)
{
  __shared__ float hrow[1024];
  __shared__ float part[64][5];
  __shared__ float h1[64];
  __shared__ float logit[10];
  int r = blockIdx.x, tid = threadIdx.x;
  for (int i = tid; i < 1024; i += 256) {
    float v = (float)hbuf[(size_t)r * HH + i];
    hrow[i] = v > 0.f ? v : 0.f;
  }
  __syncthreads();
  int n = tid & 63, q = tid >> 6;
  float s = 0.f;
  for (int i = 0; i < 256; ++i) s += hrow[q * 256 + i] * W1T[(q * 256 + i) * 64 + n];
  part[n][q] = s;
  __syncthreads();
  if (tid < 64) {
    float v = part[tid][0] + part[tid][1] + part[tid][2] + part[tid][3] + b1[tid];
    h1[tid] = v > 0.f ? v : 0.f;
  }
  __syncthreads();
  if (tid < 10) {
    float s2 = b2[tid];
    for (int k = 0; k < 64; ++k) s2 += h1[k] * W2[tid * 64 + k];
    logit[tid] = s2;
  }
  __syncthreads();
  if (tid < 10) {
    float m = logit[0];
    for (int i = 1; i < 10; ++i) m = fmaxf(m, logit[i]);
    float sum = 0.f;
    for (int i = 0; i < 10; ++i) sum += __expf(logit[i] - m);
    out[r * 10 + tid] = __expf(logit[tid] - m) / sum;
  }
}

extern "C" void kernel_launch(void* const* d_in, const int* in_sizes, int n_in,
                              void* d_out, int out_size, void* d_ws, size_t ws_size,
                              hipStream_t stream) {
  const float* x   = (const float*)d_in[0];
  const float* Wfx = (const float*)d_in[1];
  const float* Wfh = (const float*)d_in[2];
  const float* bf  = (const float*)d_in[3];
  const float* Wix = (const float*)d_in[4];
  const float* Wih = (const float*)d_in[5];
  const float* bi  = (const float*)d_in[6];
  const float* Wox = (const float*)d_in[7];
  const float* Woh = (const float*)d_in[8];
  const float* bo  = (const float*)d_in[9];
  const float* Wcx = (const float*)d_in[10];
  const float* Wch = (const float*)d_in[11];
  const float* bc  = (const float*)d_in[12];
  const float* W1  = (const float*)d_in[13];
  const float* b1  = (const float*)d_in[14];
  const float* W2  = (const float*)d_in[15];
  const float* b2  = (const float*)d_in[16];
  (void)in_sizes; (void)n_in; (void)out_size;

  char* ws = (char*)d_ws;
  h16* Wx = (h16*)(ws + WX_OFF);
  h16* Wh = (h16*)(ws + WH_OFF);
  float* bias = (float*)(ws + BIAS_OFF);
  float* W1T = (float*)(ws + W1T_OFF);
  h16* hbuf = (h16*)(ws + HBUF_OFF);
  unsigned short* arr = (unsigned short*)(ws + ARR_OFF);
  h16* xh = (h16*)(ws + XH_OFF);
  const int use_xh = (ws_size >= XH_END) ? 1 : 0;

  hipMemsetAsync(arr, 0, 4096, stream);   // 8 groups x 256 u16 slots
  k_prep<<<4096, 256, 0, stream>>>(Wfx, Wfh, bf, Wix, Wih, bi, Wox, Woh, bo, Wcx, Wch, bc, W1,
                                   Wx, Wh, bias, W1T);
  if (use_xh) k_castx<<<8192, 256, 0, stream>>>(x, xh);

  (void)hipFuncSetAttribute(reinterpret_cast<const void*>(&k_lstm<1>),
                            hipFuncAttributeMaxDynamicSharedMemorySize, SMEM_BYTES);
  (void)hipFuncSetAttribute(reinterpret_cast<const void*>(&k_lstm<0>),
                            hipFuncAttributeMaxDynamicSharedMemorySize, SMEM_BYTES);
  if (use_xh)
    k_lstm<1><<<256, 512, SMEM_BYTES, stream>>>(x, xh, Wx, Wh, bias, hbuf, arr);
  else
    k_lstm<0><<<256, 512, SMEM_BYTES, stream>>>(x, xh, Wx, Wh, bias, hbuf, arr);

  // h(T-1) lives in parity buffer (TT-1)&1 == 1
  k_head<<<256, 256, 0, stream>>>(hbuf + HSTRIDE, W1T, b1, W2, b2, (float*)d_out);
}